// Round 4
// baseline (909.331 us; speedup 1.0000x reference)
//
#include <hip/hip_runtime.h>
#include <hip/hip_bf16.h>
#include <math.h>

// MLA forward, S=4096, DIM=2048, 16 heads, qk=192 (128 nope + 64 rope), v=128, kv_lora=512.
// bf16 MFMA; NT GEMMs for projections; fused flash attention (online softmax, causal)
// with T14 register-staged prefetch (issue next K/V tile's global loads before compute,
// commit to LDS after the barrier). K/V stored pre-swizzled (chunk XOR) so ds_read_b128
// is bank-conflict-free.

constexpr int SEQ = 4096;

typedef __bf16 bf16x8 __attribute__((ext_vector_type(8)));
typedef float f32x4 __attribute__((ext_vector_type(4)));

__device__ __forceinline__ void gload16(const __bf16* g, __bf16* l) {
  __builtin_amdgcn_global_load_lds(
      (__attribute__((address_space(1))) void*)const_cast<__bf16*>(g),
      (__attribute__((address_space(3))) void*)l, 16, 0, 0);
}

// ---------------- elementwise / prep kernels ----------------

__global__ void convert_bf16(const float* __restrict__ in, __bf16* __restrict__ out, size_t n) {
  size_t i = ((size_t)blockIdx.x * blockDim.x + threadIdx.x) * 8;
  if (i >= n) return;
  float4 a = *(const float4*)(in + i);
  float4 b = *(const float4*)(in + i + 4);
  bf16x8 v = { (__bf16)a.x,(__bf16)a.y,(__bf16)a.z,(__bf16)a.w,
               (__bf16)b.x,(__bf16)b.y,(__bf16)b.z,(__bf16)b.w };
  *(bf16x8*)(out + i) = v;
}

// in[K][N] fp32 (row stride N) -> out[Nout][K] bf16, rows n>=N zero-padded.
__global__ void tconv(const float* __restrict__ in, __bf16* __restrict__ out,
                      int K, int N, int Nout) {
  __shared__ float tile[32][33];
  const int kb = blockIdx.x * 32;
  const int nb = blockIdx.y * 32;
  const int tx = threadIdx.x, ty = threadIdx.y;
#pragma unroll
  for (int i = 0; i < 32; i += 8) {
    const int k = kb + ty + i, n = nb + tx;
    tile[ty + i][tx] = (n < N) ? in[(size_t)k * N + n] : 0.f;
  }
  __syncthreads();
#pragma unroll
  for (int i = 0; i < 32; i += 8) {
    const int n = nb + ty + i, k = kb + tx;
    out[(size_t)n * K + k] = (__bf16)tile[tx][ty + i];
  }
}

// in-place RoPE on q_attn[h][s][128..191]; block = 512 thr (16 heads x 32 pairs), grid = SEQ
__global__ void rope_q(__bf16* __restrict__ q, const float* __restrict__ fcos,
                       const float* __restrict__ fsin) {
  const int s = blockIdx.x;
  const int t = threadIdx.x;
  const int h = t >> 5, j = t & 31;
  const float c = fcos[s * 32 + j], sn = fsin[s * 32 + j];
  __bf16* p = q + ((size_t)h * SEQ + s) * 192 + 128 + 2 * j;
  const float xr = (float)p[0], xi = (float)p[1];
  p[0] = (__bf16)(xr * c - xi * sn);
  p[1] = (__bf16)(xr * sn + xi * c);
}

// RMS-norm kv_lat -> ckv bf16; RoPE k_pe -> kpe bf16. block 256, grid SEQ.
__global__ void normrope_kv(const float* __restrict__ kvraw, const float* __restrict__ w,
                            const float* __restrict__ fcos, const float* __restrict__ fsin,
                            __bf16* __restrict__ ckv, __bf16* __restrict__ kpe) {
  const int s = blockIdx.x, t = threadIdx.x;
  const float* row = kvraw + (size_t)s * 640;
  const float x0 = row[t], x1 = row[t + 256];
  __shared__ float red[256];
  red[t] = x0 * x0 + x1 * x1;
  __syncthreads();
  for (int k = 128; k > 0; k >>= 1) { if (t < k) red[t] += red[t + k]; __syncthreads(); }
  const float r = rsqrtf(red[0] / 512.f + 1e-6f);
  ckv[(size_t)s * 512 + t]       = (__bf16)(x0 * r * w[t]);
  ckv[(size_t)s * 512 + t + 256] = (__bf16)(x1 * r * w[t + 256]);
  if (t < 32) {
    const float c = fcos[s * 32 + t], sn = fsin[s * 32 + t];
    const float xr = row[512 + 2 * t], xi = row[513 + 2 * t];
    kpe[(size_t)s * 64 + 2 * t]     = (__bf16)(xr * c - xi * sn);
    kpe[(size_t)s * 64 + 2 * t + 1] = (__bf16)(xr * sn + xi * c);
  }
}

// Scatter to SWIZZLED attention layouts:
//  katt[h][s][col'] with col' = ((col/8 ^ (s&7))*8 | col%8)   (192 cols: 128 nope + 64 rope)
//  vT[h][d][s'] with s' swizzling the 8-elem chunk within each 64-kv tile by (d&7)
__global__ void scatter_kv(const __bf16* __restrict__ kvup, const __bf16* __restrict__ kpe,
                           __bf16* __restrict__ katt, __bf16* __restrict__ vT) {
  const int s = blockIdx.x, h = blockIdx.y, t = threadIdx.x;
  const size_t kbase = ((size_t)h * SEQ + s) * 192;
  const int r7 = s & 7;
  if (t < 128) {
    const int col = t;
    katt[kbase + ((((col >> 3) ^ r7) << 3) | (col & 7))] =
        kvup[(size_t)s * 4096 + h * 256 + t];
    const int sw = (s & ~63) | ((((s >> 3) & 7) ^ (t & 7)) << 3) | (s & 7);
    vT[((size_t)h * 128 + t) * SEQ + sw] = kvup[(size_t)s * 4096 + h * 256 + 128 + t];
  } else {
    const int col = t;  // 128..191
    katt[kbase + ((((col >> 3) ^ r7) << 3) | (col & 7))] = kpe[(size_t)s * 64 + (t - 128)];
  }
}

// ---------------- NT GEMM: C[M][N] = A[M][K] * B[N][K]^T ----------------
// 128x128 tile, 4 waves (2x2), BK=64, global_load_lds(16B) staging.
// OUT_MODE 0: fp32 row-major; 1: bf16 row-major; 2: bf16 q-head layout [c/192][r][c%192]
template<int OUT_MODE>
__global__ __launch_bounds__(256) void gemm_nt(
    const __bf16* __restrict__ A, int lda,
    const __bf16* __restrict__ B, int ldb,
    void* __restrict__ Cout, int ldc,
    int K, float scale)
{
  const int row0 = blockIdx.y * 128;
  const int col0 = blockIdx.x * 128;

  __shared__ __bf16 As[128 * 64];
  __shared__ __bf16 Bs[128 * 64];

  const int t = threadIdx.x;
  const int lane = t & 63;
  const int wid = t >> 6;
  const int wr = (wid >> 1) * 64;
  const int wc = (wid & 1) * 64;

  const int ar = t >> 3;          // 0..31
  const int ac = (t & 7) * 8;     // 0..56
  const __bf16* ag = A + (size_t)(row0 + ar) * lda + ac;
  const __bf16* bg = B + (size_t)(col0 + ar) * ldb + ac;
  const int loff = ar * 64 + ac;

  f32x4 acc[4][4] = {};

  for (int k0 = 0; k0 < K; k0 += 64) {
#pragma unroll
    for (int i = 0; i < 4; ++i) {
      gload16(ag + (size_t)(i * 32) * lda + k0, &As[loff + i * 32 * 64]);
      gload16(bg + (size_t)(i * 32) * ldb + k0, &Bs[loff + i * 32 * 64]);
    }
    __syncthreads();
    const int ro = lane & 15;
#pragma unroll
    for (int ks = 0; ks < 2; ++ks) {
      const int ko = ks * 32 + (lane >> 4) * 8;
      bf16x8 af[4], bfr[4];
#pragma unroll
      for (int x = 0; x < 4; ++x) {
        af[x]  = *(const bf16x8*)&As[(wr + x * 16 + ro) * 64 + ko];
        bfr[x] = *(const bf16x8*)&Bs[(wc + x * 16 + ro) * 64 + ko];
      }
#pragma unroll
      for (int x = 0; x < 4; ++x)
#pragma unroll
        for (int y = 0; y < 4; ++y)
          acc[x][y] = __builtin_amdgcn_mfma_f32_16x16x32_bf16(af[x], bfr[y], acc[x][y], 0, 0, 0);
    }
    __syncthreads();
  }

  const int lr = (lane >> 4) * 4;
  const int lc = lane & 15;
#pragma unroll
  for (int x = 0; x < 4; ++x)
#pragma unroll
    for (int y = 0; y < 4; ++y)
#pragma unroll
      for (int j = 0; j < 4; ++j) {
        const int r = row0 + wr + x * 16 + lr + j;
        const int c = col0 + wc + y * 16 + lc;
        const float v = acc[x][y][j] * scale;
        if (OUT_MODE == 0) {
          ((float*)Cout)[(size_t)r * ldc + c] = v;
        } else if (OUT_MODE == 1) {
          ((__bf16*)Cout)[(size_t)r * ldc + c] = (__bf16)v;
        } else {
          const int h = c / 192;
          const int d = c - h * 192;
          ((__bf16*)Cout)[((size_t)h * SEQ + r) * 192 + d] = (__bf16)v;
        }
      }
}

// ---------------- fused flash attention (causal) ----------------
// Grid 512: 16 heads x 32 q-tiles of 128 rows. 4 waves x 32 rows. KV-tile 64.
// T14 register-staged prefetch: global->VGPR loads for tile t+1 issued before the
// compute of tile t; committed to LDS via ds_write_b128 at the top of iter t+1.
// LDS: K 24.5KB + V 16KB + P 16KB = 57KB -> 2 blocks/CU.
__global__ __launch_bounds__(256, 2) void flash_attn(
    const __bf16* __restrict__ Q, const __bf16* __restrict__ Kt,
    const __bf16* __restrict__ Vt, __bf16* __restrict__ O)
{
  __shared__ __bf16 Ks[64 * 192];
  __shared__ __bf16 Vs[128 * 64];
  __shared__ __bf16 Ps[128 * 64];

  const int bid = blockIdx.x;
  const int slot = bid >> 3;          // 0..63
  const int xcd  = bid & 7;
  const int h    = xcd * 2 + (slot & 1);   // 2 heads per XCD -> K/V L2-resident
  const int sl2  = slot >> 1;              // 0..31
  const int qt   = (slot < 32) ? (31 - sl2) : (sl2 - 16);
  const int q0   = qt * 128;

  const int t = threadIdx.x;
  const int lane = t & 63;
  const int w = t >> 6;
  const int l15 = lane & 15;
  const int lg  = lane >> 4;    // 0..3

  // staging chunk ids (identical mapping to the r3 gload_lds version)
  int gch[6];
#pragma unroll
  for (int j = 0; j < 6; ++j) gch[j] = ((j << 2) + w) * 64 + lane;

  // Q fragments in registers: rows q0 + w*32 + m*16 + l15, k = kf*32 + lg*8
  bf16x8 qf[2][6];
  {
    const __bf16* qbase = Q + ((size_t)h * SEQ + q0 + w * 32 + l15) * 192 + lg * 8;
#pragma unroll
    for (int m = 0; m < 2; ++m)
#pragma unroll
      for (int kf = 0; kf < 6; ++kf)
        qf[m][kf] = *(const bf16x8*)(qbase + (size_t)m * 16 * 192 + kf * 32);
  }

  f32x4 o_acc[2][8] = {};
  float mrow[2][4], lsum[2][4];
#pragma unroll
  for (int m = 0; m < 2; ++m)
#pragma unroll
    for (int j = 0; j < 4; ++j) { mrow[m][j] = -1e30f; lsum[m][j] = 0.f; }

  const __bf16* kh = Kt + (size_t)h * SEQ * 192;
  const __bf16* vh = Vt + (size_t)h * 128 * SEQ;
  const int kv_end = q0 + 128;

  // prologue: load tile 0 into staging registers
  bf16x8 kreg[6], vreg[4];
#pragma unroll
  for (int j = 0; j < 6; ++j) kreg[j] = *(const bf16x8*)(kh + gch[j] * 8);
#pragma unroll
  for (int j = 0; j < 4; ++j)
    vreg[j] = *(const bf16x8*)(vh + (size_t)(gch[j] >> 3) * SEQ + (gch[j] & 7) * 8);

  for (int kv0 = 0; kv0 < kv_end; kv0 += 64) {
    // commit staged regs to LDS (compiler inserts the vmcnt wait here)
#pragma unroll
    for (int j = 0; j < 6; ++j) *(bf16x8*)&Ks[gch[j] * 8] = kreg[j];
#pragma unroll
    for (int j = 0; j < 4; ++j) *(bf16x8*)&Vs[gch[j] * 8] = vreg[j];
    __syncthreads();

    // prefetch next tile into registers — latency hides under the compute below
    if (kv0 + 64 < kv_end) {
      const __bf16* ksrc = kh + (size_t)(kv0 + 64) * 192;
#pragma unroll
      for (int j = 0; j < 6; ++j) kreg[j] = *(const bf16x8*)(ksrc + gch[j] * 8);
      const __bf16* vsrc = vh + kv0 + 64;
#pragma unroll
      for (int j = 0; j < 4; ++j)
        vreg[j] = *(const bf16x8*)(vsrc + (size_t)(gch[j] >> 3) * SEQ + (gch[j] & 7) * 8);
    }

    // scores S = Q K^T : per wave 32x64 (scale already folded into Q)
    f32x4 s[2][4] = {};
#pragma unroll
    for (int kf = 0; kf < 6; ++kf) {
      bf16x8 kb[4];
#pragma unroll
      for (int n = 0; n < 4; ++n) {
        const int r = n * 16 + l15;
        const int ch = (kf * 4 + lg) ^ (r & 7);
        kb[n] = *(const bf16x8*)&Ks[r * 192 + ch * 8];
      }
#pragma unroll
      for (int m = 0; m < 2; ++m)
#pragma unroll
        for (int n = 0; n < 4; ++n)
          s[m][n] = __builtin_amdgcn_mfma_f32_16x16x32_bf16(qf[m][kf], kb[n], s[m][n], 0, 0, 0);
    }

    // causal mask (wave-uniform skip below diagonal)
    if (kv0 + 63 > q0 + w * 32) {
#pragma unroll
      for (int m = 0; m < 2; ++m)
#pragma unroll
        for (int n = 0; n < 4; ++n)
#pragma unroll
          for (int j = 0; j < 4; ++j) {
            const int r = q0 + w * 32 + m * 16 + lg * 4 + j;
            const int c = kv0 + n * 16 + l15;
            if (c > r) s[m][n][j] = -1e30f;
          }
    }

    // online softmax; row r = m*16 + lg*4 + j lives across the 16 lanes sharing lg
#pragma unroll
    for (int m = 0; m < 2; ++m)
#pragma unroll
      for (int j = 0; j < 4; ++j) {
        float pm = fmaxf(fmaxf(s[m][0][j], s[m][1][j]), fmaxf(s[m][2][j], s[m][3][j]));
        pm = fmaxf(pm, __shfl_xor(pm, 1));
        pm = fmaxf(pm, __shfl_xor(pm, 2));
        pm = fmaxf(pm, __shfl_xor(pm, 4));
        pm = fmaxf(pm, __shfl_xor(pm, 8));
        const float nm  = fmaxf(mrow[m][j], pm);
        const float fac = __expf(mrow[m][j] - nm);
        mrow[m][j] = nm;
        float rs = 0.f;
#pragma unroll
        for (int n = 0; n < 4; ++n) {
          const float e = __expf(s[m][n][j] - nm);
          s[m][n][j] = e;
          rs += e;
        }
        rs += __shfl_xor(rs, 1);
        rs += __shfl_xor(rs, 2);
        rs += __shfl_xor(rs, 4);
        rs += __shfl_xor(rs, 8);
        lsum[m][j] = lsum[m][j] * fac + rs;
#pragma unroll
        for (int vn = 0; vn < 8; ++vn) o_acc[m][vn][j] *= fac;
      }

    // P (C-layout) -> LDS bf16, XOR-swizzled; per-wave private region, no barrier needed
#pragma unroll
    for (int m = 0; m < 2; ++m)
#pragma unroll
      for (int n = 0; n < 4; ++n)
#pragma unroll
        for (int j = 0; j < 4; ++j) {
          const int r = w * 32 + m * 16 + lg * 4 + j;
          const int c = n * 16 + l15;
          Ps[r * 64 + (c ^ ((r & 7) << 3))] = (__bf16)s[m][n][j];
        }

    // PV: O += P @ V  (A = P rows, B = V^T rows = v-cols)
#pragma unroll
    for (int kf2 = 0; kf2 < 2; ++kf2) {
      bf16x8 pa[2];
#pragma unroll
      for (int m = 0; m < 2; ++m) {
        const int r = w * 32 + m * 16 + l15;
        const int e = (kf2 * 32 + lg * 8) ^ ((r & 7) << 3);
        pa[m] = *(const bf16x8*)&Ps[r * 64 + e];
      }
#pragma unroll
      for (int vn = 0; vn < 8; ++vn) {
        const int r = vn * 16 + l15;
        const int ch = (kf2 * 4 + lg) ^ (r & 7);
        const bf16x8 vb = *(const bf16x8*)&Vs[r * 64 + ch * 8];
#pragma unroll
        for (int m = 0; m < 2; ++m)
          o_acc[m][vn] = __builtin_amdgcn_mfma_f32_16x16x32_bf16(pa[m], vb, o_acc[m][vn], 0, 0, 0);
      }
    }
    __syncthreads();
  }

  // epilogue: normalize and store to ob[4096][2048] at head column offset
#pragma unroll
  for (int m = 0; m < 2; ++m)
#pragma unroll
    for (int j = 0; j < 4; ++j) {
      const float inv = 1.0f / lsum[m][j];
      const size_t rbase = (size_t)(q0 + w * 32 + m * 16 + lg * 4 + j) * 2048 + h * 128 + l15;
#pragma unroll
      for (int vn = 0; vn < 8; ++vn)
        O[rbase + vn * 16] = (__bf16)(o_acc[m][vn][j] * inv);
    }
}

// ---------------- launch ----------------

extern "C" void kernel_launch(void* const* d_in, const int* in_sizes, int n_in,
                              void* d_out, int out_size, void* d_ws, size_t ws_size,
                              hipStream_t stream) {
  const float* x    = (const float*)d_in[0];
  const float* fcos = (const float*)d_in[1];
  const float* fsin = (const float*)d_in[2];
  // d_in[3] = mask: implied by causal structure, unused
  const float* wq   = (const float*)d_in[4];
  const float* wkva = (const float*)d_in[5];
  const float* kvw  = (const float*)d_in[6];
  const float* wkvb = (const float*)d_in[7];
  const float* wo   = (const float*)d_in[8];
  float* out = (float*)d_out;
  char* ws = (char*)d_ws;

  __bf16* xb    = (__bf16*)(ws + 0);           // 16,777,216
  __bf16* wqT   = (__bf16*)(ws + 16777216);    // 12,582,912  [3072][2048]
  __bf16* wkvaT = (__bf16*)(ws + 29360128);    //  2,621,440  [640][2048] (zero-padded)
  __bf16* wkvbT = (__bf16*)(ws + 31981568);    //  4,194,304  [4096][512]
  __bf16* woT   = (__bf16*)(ws + 36175872);    //  8,388,608  [2048][2048]
  __bf16* qatt  = (__bf16*)(ws + 44564480);    // 25,165,824  [16][4096][192]
  __bf16* katt  = (__bf16*)(ws + 69730304);    // 25,165,824  [16][4096][192] swizzled
  __bf16* vT    = (__bf16*)(ws + 94896128);    // 16,777,216  [16][128][4096] swizzled
  __bf16* ob    = (__bf16*)(ws + 111673344);   // 16,777,216  [4096][2048]
  __bf16* ckv   = (__bf16*)(ws + 128450560);   //  4,194,304  [4096][512]
  __bf16* kpe   = (__bf16*)(ws + 132644864);   //    524,288  [4096][64]
  float*  kvraw = (float*)(ws + 133169152);    // 10,485,760  [4096][640]
  __bf16* kvup  = (__bf16*)(ws + 143654912);   // 33,554,432  [4096][4096]
  // total 177,209,344 bytes

  const double ms = 0.1 * log(40.0) + 1.0;
  const float SM_SCALE = (float)((1.0 / sqrt(192.0)) * ms * ms);

  convert_bf16<<<4096, 256, 0, stream>>>(x, xb, (size_t)SEQ * 2048);
  tconv<<<dim3(64, 96),  dim3(32, 8), 0, stream>>>(wq,   wqT,   2048, 3072, 3072);
  tconv<<<dim3(64, 20),  dim3(32, 8), 0, stream>>>(wkva, wkvaT, 2048, 576,  640);
  tconv<<<dim3(16, 128), dim3(32, 8), 0, stream>>>(wkvb, wkvbT, 512,  4096, 4096);
  tconv<<<dim3(64, 64),  dim3(32, 8), 0, stream>>>(wo,   woT,   2048, 2048, 2048);

  // q = x @ wq (softmax scale folded in; rope commutes with scalar), head layout, then RoPE
  gemm_nt<2><<<dim3(24, 32), 256, 0, stream>>>(xb, 2048, wqT, 2048, qatt, 192, 2048, SM_SCALE);
  rope_q<<<SEQ, 512, 0, stream>>>(qatt, fcos, fsin);
  // kv = x @ wkv_a (fp32)
  gemm_nt<0><<<dim3(5, 32), 256, 0, stream>>>(xb, 2048, wkvaT, 2048, kvraw, 640, 2048, 1.f);
  normrope_kv<<<SEQ, 256, 0, stream>>>(kvraw, kvw, fcos, fsin, ckv, kpe);
  // kv_up = rms_norm(kv_lat) @ wkv_b (bf16)
  gemm_nt<1><<<dim3(32, 32), 256, 0, stream>>>(ckv, 512, wkvbT, 512, kvup, 4096, 512, 1.f);
  scatter_kv<<<dim3(SEQ, 16), 192, 0, stream>>>(kvup, kpe, katt, vT);

  // fused causal flash attention -> ob
  flash_attn<<<512, 256, 0, stream>>>(qatt, katt, vT, ob);

  // out = o @ wo (fp32)
  gemm_nt<0><<<dim3(16, 32), 256, 0, stream>>>(ob, 2048, woT, 2048, out, 2048, 2048, 1.f);
}

// Round 5
// 723.308 us; speedup vs baseline: 1.2572x; 1.2572x over previous
//
#include <hip/hip_runtime.h>
#include <hip/hip_bf16.h>
#include <math.h>

// MLA forward, S=4096, DIM=2048, 16 heads, qk=192 (128 nope + 64 rope), v=128, kv_lora=512.
// bf16 MFMA; NT GEMMs for projections; fused flash attention (online softmax, causal)
// with double-buffered global_load_lds staging (T3 2-phase: stage t+1 before compute t,
// one __syncthreads per iter). Grid 256: one block per (head, qt-pair), 66 kv-iters each.
// K/V stored pre-swizzled (chunk XOR) so ds_read_b128 is bank-conflict-free.

constexpr int SEQ = 4096;

typedef __bf16 bf16x8 __attribute__((ext_vector_type(8)));
typedef float f32x4 __attribute__((ext_vector_type(4)));

__device__ __forceinline__ void gload16(const __bf16* g, __bf16* l) {
  __builtin_amdgcn_global_load_lds(
      (__attribute__((address_space(1))) void*)const_cast<__bf16*>(g),
      (__attribute__((address_space(3))) void*)l, 16, 0, 0);
}

// ---------------- elementwise / prep kernels ----------------

__global__ void convert_bf16(const float* __restrict__ in, __bf16* __restrict__ out, size_t n) {
  size_t i = ((size_t)blockIdx.x * blockDim.x + threadIdx.x) * 8;
  if (i >= n) return;
  float4 a = *(const float4*)(in + i);
  float4 b = *(const float4*)(in + i + 4);
  bf16x8 v = { (__bf16)a.x,(__bf16)a.y,(__bf16)a.z,(__bf16)a.w,
               (__bf16)b.x,(__bf16)b.y,(__bf16)b.z,(__bf16)b.w };
  *(bf16x8*)(out + i) = v;
}

// in[K][N] fp32 (row stride N) -> out[Nout][K] bf16, rows n>=N zero-padded.
__global__ void tconv(const float* __restrict__ in, __bf16* __restrict__ out,
                      int K, int N, int Nout) {
  __shared__ float tile[32][33];
  const int kb = blockIdx.x * 32;
  const int nb = blockIdx.y * 32;
  const int tx = threadIdx.x, ty = threadIdx.y;
#pragma unroll
  for (int i = 0; i < 32; i += 8) {
    const int k = kb + ty + i, n = nb + tx;
    tile[ty + i][tx] = (n < N) ? in[(size_t)k * N + n] : 0.f;
  }
  __syncthreads();
#pragma unroll
  for (int i = 0; i < 32; i += 8) {
    const int n = nb + ty + i, k = kb + tx;
    out[(size_t)n * K + k] = (__bf16)tile[tx][ty + i];
  }
}

// in-place RoPE on q_attn[h][s][128..191]; block = 512 thr (16 heads x 32 pairs), grid = SEQ
__global__ void rope_q(__bf16* __restrict__ q, const float* __restrict__ fcos,
                       const float* __restrict__ fsin) {
  const int s = blockIdx.x;
  const int t = threadIdx.x;
  const int h = t >> 5, j = t & 31;
  const float c = fcos[s * 32 + j], sn = fsin[s * 32 + j];
  __bf16* p = q + ((size_t)h * SEQ + s) * 192 + 128 + 2 * j;
  const float xr = (float)p[0], xi = (float)p[1];
  p[0] = (__bf16)(xr * c - xi * sn);
  p[1] = (__bf16)(xr * sn + xi * c);
}

// RMS-norm kv_lat -> ckv bf16; RoPE k_pe -> kpe bf16. block 256, grid SEQ.
__global__ void normrope_kv(const float* __restrict__ kvraw, const float* __restrict__ w,
                            const float* __restrict__ fcos, const float* __restrict__ fsin,
                            __bf16* __restrict__ ckv, __bf16* __restrict__ kpe) {
  const int s = blockIdx.x, t = threadIdx.x;
  const float* row = kvraw + (size_t)s * 640;
  const float x0 = row[t], x1 = row[t + 256];
  __shared__ float red[256];
  red[t] = x0 * x0 + x1 * x1;
  __syncthreads();
  for (int k = 128; k > 0; k >>= 1) { if (t < k) red[t] += red[t + k]; __syncthreads(); }
  const float r = rsqrtf(red[0] / 512.f + 1e-6f);
  ckv[(size_t)s * 512 + t]       = (__bf16)(x0 * r * w[t]);
  ckv[(size_t)s * 512 + t + 256] = (__bf16)(x1 * r * w[t + 256]);
  if (t < 32) {
    const float c = fcos[s * 32 + t], sn = fsin[s * 32 + t];
    const float xr = row[512 + 2 * t], xi = row[513 + 2 * t];
    kpe[(size_t)s * 64 + 2 * t]     = (__bf16)(xr * c - xi * sn);
    kpe[(size_t)s * 64 + 2 * t + 1] = (__bf16)(xr * sn + xi * c);
  }
}

// Scatter to SWIZZLED attention layouts:
//  katt[h][s][col'] with col' = ((col/8 ^ (s&7))*8 | col%8)   (192 cols: 128 nope + 64 rope)
//  vT[h][d][s'] with s' swizzling the 8-elem chunk within each 64-kv tile by (d&7)
__global__ void scatter_kv(const __bf16* __restrict__ kvup, const __bf16* __restrict__ kpe,
                           __bf16* __restrict__ katt, __bf16* __restrict__ vT) {
  const int s = blockIdx.x, h = blockIdx.y, t = threadIdx.x;
  const size_t kbase = ((size_t)h * SEQ + s) * 192;
  const int r7 = s & 7;
  if (t < 128) {
    const int col = t;
    katt[kbase + ((((col >> 3) ^ r7) << 3) | (col & 7))] =
        kvup[(size_t)s * 4096 + h * 256 + t];
    const int sw = (s & ~63) | ((((s >> 3) & 7) ^ (t & 7)) << 3) | (s & 7);
    vT[((size_t)h * 128 + t) * SEQ + sw] = kvup[(size_t)s * 4096 + h * 256 + 128 + t];
  } else {
    const int col = t;  // 128..191
    katt[kbase + ((((col >> 3) ^ r7) << 3) | (col & 7))] = kpe[(size_t)s * 64 + (t - 128)];
  }
}

// ---------------- NT GEMM: C[M][N] = A[M][K] * B[N][K]^T ----------------
// 128x128 tile, 4 waves (2x2), BK=64, global_load_lds(16B) staging.
// OUT_MODE 0: fp32 row-major; 1: bf16 row-major; 2: bf16 q-head layout [c/192][r][c%192]
template<int OUT_MODE>
__global__ __launch_bounds__(256) void gemm_nt(
    const __bf16* __restrict__ A, int lda,
    const __bf16* __restrict__ B, int ldb,
    void* __restrict__ Cout, int ldc,
    int K, float scale)
{
  const int row0 = blockIdx.y * 128;
  const int col0 = blockIdx.x * 128;

  __shared__ __bf16 As[128 * 64];
  __shared__ __bf16 Bs[128 * 64];

  const int t = threadIdx.x;
  const int lane = t & 63;
  const int wid = t >> 6;
  const int wr = (wid >> 1) * 64;
  const int wc = (wid & 1) * 64;

  const int ar = t >> 3;          // 0..31
  const int ac = (t & 7) * 8;     // 0..56
  const __bf16* ag = A + (size_t)(row0 + ar) * lda + ac;
  const __bf16* bg = B + (size_t)(col0 + ar) * ldb + ac;
  const int loff = ar * 64 + ac;

  f32x4 acc[4][4] = {};

  for (int k0 = 0; k0 < K; k0 += 64) {
#pragma unroll
    for (int i = 0; i < 4; ++i) {
      gload16(ag + (size_t)(i * 32) * lda + k0, &As[loff + i * 32 * 64]);
      gload16(bg + (size_t)(i * 32) * ldb + k0, &Bs[loff + i * 32 * 64]);
    }
    __syncthreads();
    const int ro = lane & 15;
#pragma unroll
    for (int ks = 0; ks < 2; ++ks) {
      const int ko = ks * 32 + (lane >> 4) * 8;
      bf16x8 af[4], bfr[4];
#pragma unroll
      for (int x = 0; x < 4; ++x) {
        af[x]  = *(const bf16x8*)&As[(wr + x * 16 + ro) * 64 + ko];
        bfr[x] = *(const bf16x8*)&Bs[(wc + x * 16 + ro) * 64 + ko];
      }
#pragma unroll
      for (int x = 0; x < 4; ++x)
#pragma unroll
        for (int y = 0; y < 4; ++y)
          acc[x][y] = __builtin_amdgcn_mfma_f32_16x16x32_bf16(af[x], bfr[y], acc[x][y], 0, 0, 0);
    }
    __syncthreads();
  }

  const int lr = (lane >> 4) * 4;
  const int lc = lane & 15;
#pragma unroll
  for (int x = 0; x < 4; ++x)
#pragma unroll
    for (int y = 0; y < 4; ++y)
#pragma unroll
      for (int j = 0; j < 4; ++j) {
        const int r = row0 + wr + x * 16 + lr + j;
        const int c = col0 + wc + y * 16 + lc;
        const float v = acc[x][y][j] * scale;
        if (OUT_MODE == 0) {
          ((float*)Cout)[(size_t)r * ldc + c] = v;
        } else if (OUT_MODE == 1) {
          ((__bf16*)Cout)[(size_t)r * ldc + c] = (__bf16)v;
        } else {
          const int h = c / 192;
          const int d = c - h * 192;
          ((__bf16*)Cout)[((size_t)h * SEQ + r) * 192 + d] = (__bf16)v;
        }
      }
}

// ---------------- fused flash attention (causal) ----------------
// Grid 256: one block per (head, qt-pair). Each block: qt = 31-u then qt = u
// (66 kv-iters total, uniform across all blocks; 1 block/CU).
// Double-buffered global_load_lds: stage tile t+1 into buf cur^1 BEFORE computing
// tile t from buf cur; the single __syncthreads per iter drains vmcnt after the
// loads had the whole compute phase to land. Zero staging registers -> no spills.
// LDS: K 2x24.5KB + V 2x16KB + P 16KB = 96KB -> 1 block/CU.
__global__ __launch_bounds__(256, 2) void flash_attn(
    const __bf16* __restrict__ Q, const __bf16* __restrict__ Kt,
    const __bf16* __restrict__ Vt, __bf16* __restrict__ O)
{
  __shared__ __bf16 Ks[2 * 64 * 192];
  __shared__ __bf16 Vs[2 * 128 * 64];
  __shared__ __bf16 Ps[128 * 64];

  const int bid  = blockIdx.x;
  const int xcd  = bid & 7;
  const int slot = bid >> 3;               // 0..31
  const int h    = xcd * 2 + (slot & 1);   // 2 heads per XCD -> K/V mostly L2-resident
  const int u    = slot >> 1;              // 0..15 (q-tile pair id)

  const int t = threadIdx.x;
  const int lane = t & 63;
  const int w = t >> 6;
  const int l15 = lane & 15;
  const int lg  = lane >> 4;    // 0..3

  // staging chunk ids (same mapping as the proven r3 version)
  int gch[6];
#pragma unroll
  for (int j = 0; j < 6; ++j) gch[j] = ((j << 2) + w) * 64 + lane;

  const __bf16* kh = Kt + (size_t)h * SEQ * 192;
  const __bf16* vh = Vt + (size_t)h * 128 * SEQ;

#pragma unroll 1
  for (int pass = 0; pass < 2; ++pass) {
    const int qt = pass ? u : (31 - u);
    const int q0 = qt << 7;
    const int nt = (q0 + 128) >> 6;   // kv tiles for this q-tile

    // Q fragments in registers: rows q0 + w*32 + m*16 + l15, k = kf*32 + lg*8
    bf16x8 qf[2][6];
    {
      const __bf16* qbase = Q + ((size_t)h * SEQ + q0 + w * 32 + l15) * 192 + lg * 8;
#pragma unroll
      for (int m = 0; m < 2; ++m)
#pragma unroll
        for (int kf = 0; kf < 6; ++kf)
          qf[m][kf] = *(const bf16x8*)(qbase + (size_t)m * 16 * 192 + kf * 32);
    }

    f32x4 o_acc[2][8] = {};
    float mrow[2][4], lsum[2][4];
#pragma unroll
    for (int m = 0; m < 2; ++m)
#pragma unroll
      for (int j = 0; j < 4; ++j) { mrow[m][j] = -1e30f; lsum[m][j] = 0.f; }

    // stage tile 0 into buffer 0
    {
      const __bf16* ksrc = kh;
#pragma unroll
      for (int j = 0; j < 6; ++j) gload16(ksrc + gch[j] * 8, &Ks[gch[j] * 8]);
      const __bf16* vsrc = vh;
#pragma unroll
      for (int j = 0; j < 4; ++j)
        gload16(vsrc + (size_t)(gch[j] >> 3) * SEQ + (gch[j] & 7) * 8, &Vs[gch[j] * 8]);
    }
    __syncthreads();

#pragma unroll 1
    for (int ti = 0; ti < nt; ++ti) {
      const int cur = ti & 1;
      const int kv0 = ti << 6;

      // stage NEXT tile into the other buffer (latency hides under compute below)
      if (ti + 1 < nt) {
        const int nb = cur ^ 1;
        const __bf16* ksrc = kh + (size_t)(kv0 + 64) * 192;
#pragma unroll
        for (int j = 0; j < 6; ++j)
          gload16(ksrc + gch[j] * 8, &Ks[nb * (64 * 192) + gch[j] * 8]);
        const __bf16* vsrc = vh + kv0 + 64;
#pragma unroll
        for (int j = 0; j < 4; ++j)
          gload16(vsrc + (size_t)(gch[j] >> 3) * SEQ + (gch[j] & 7) * 8,
                  &Vs[nb * (128 * 64) + gch[j] * 8]);
      }

      const __bf16* KsC = &Ks[cur * (64 * 192)];
      const __bf16* VsC = &Vs[cur * (128 * 64)];

      // scores S = Q K^T : per wave 32x64 (scale already folded into Q)
      f32x4 s[2][4] = {};
#pragma unroll
      for (int kf = 0; kf < 6; ++kf) {
        bf16x8 kb[4];
#pragma unroll
        for (int n = 0; n < 4; ++n) {
          const int r = n * 16 + l15;
          const int ch = (kf * 4 + lg) ^ (r & 7);
          kb[n] = *(const bf16x8*)&KsC[r * 192 + ch * 8];
        }
#pragma unroll
        for (int m = 0; m < 2; ++m)
#pragma unroll
          for (int n = 0; n < 4; ++n)
            s[m][n] = __builtin_amdgcn_mfma_f32_16x16x32_bf16(qf[m][kf], kb[n], s[m][n], 0, 0, 0);
      }

      // causal mask (wave-uniform skip below diagonal)
      if (kv0 + 63 > q0 + w * 32) {
#pragma unroll
        for (int m = 0; m < 2; ++m)
#pragma unroll
          for (int n = 0; n < 4; ++n)
#pragma unroll
            for (int j = 0; j < 4; ++j) {
              const int r = q0 + w * 32 + m * 16 + lg * 4 + j;
              const int c = kv0 + n * 16 + l15;
              if (c > r) s[m][n][j] = -1e30f;
            }
      }

      // online softmax; row r = m*16 + lg*4 + j lives across the 16 lanes sharing lg
#pragma unroll
      for (int m = 0; m < 2; ++m)
#pragma unroll
        for (int j = 0; j < 4; ++j) {
          float pm = fmaxf(fmaxf(s[m][0][j], s[m][1][j]), fmaxf(s[m][2][j], s[m][3][j]));
          pm = fmaxf(pm, __shfl_xor(pm, 1));
          pm = fmaxf(pm, __shfl_xor(pm, 2));
          pm = fmaxf(pm, __shfl_xor(pm, 4));
          pm = fmaxf(pm, __shfl_xor(pm, 8));
          const float nm  = fmaxf(mrow[m][j], pm);
          const float fac = __expf(mrow[m][j] - nm);
          mrow[m][j] = nm;
          float rs = 0.f;
#pragma unroll
          for (int n = 0; n < 4; ++n) {
            const float e = __expf(s[m][n][j] - nm);
            s[m][n][j] = e;
            rs += e;
          }
          rs += __shfl_xor(rs, 1);
          rs += __shfl_xor(rs, 2);
          rs += __shfl_xor(rs, 4);
          rs += __shfl_xor(rs, 8);
          lsum[m][j] = lsum[m][j] * fac + rs;
#pragma unroll
          for (int vn = 0; vn < 8; ++vn) o_acc[m][vn][j] *= fac;
        }

      // P (C-layout) -> LDS bf16, XOR-swizzled; per-wave private region, no barrier needed
#pragma unroll
      for (int m = 0; m < 2; ++m)
#pragma unroll
        for (int n = 0; n < 4; ++n)
#pragma unroll
          for (int j = 0; j < 4; ++j) {
            const int r = w * 32 + m * 16 + lg * 4 + j;
            const int c = n * 16 + l15;
            Ps[r * 64 + (c ^ ((r & 7) << 3))] = (__bf16)s[m][n][j];
          }

      // PV: O += P @ V  (A = P rows, B = V^T rows = v-cols)
#pragma unroll
      for (int kf2 = 0; kf2 < 2; ++kf2) {
        bf16x8 pa[2];
#pragma unroll
        for (int m = 0; m < 2; ++m) {
          const int r = w * 32 + m * 16 + l15;
          const int e = (kf2 * 32 + lg * 8) ^ ((r & 7) << 3);
          pa[m] = *(const bf16x8*)&Ps[r * 64 + e];
        }
#pragma unroll
        for (int vn = 0; vn < 8; ++vn) {
          const int r = vn * 16 + l15;
          const int ch = (kf2 * 4 + lg) ^ (r & 7);
          const bf16x8 vb = *(const bf16x8*)&VsC[r * 64 + ch * 8];
#pragma unroll
          for (int m = 0; m < 2; ++m)
            o_acc[m][vn] = __builtin_amdgcn_mfma_f32_16x16x32_bf16(pa[m], vb, o_acc[m][vn], 0, 0, 0);
        }
      }
      __syncthreads();   // waves aligned; also drains next-tile staging loads
    }

    // epilogue: normalize and store to ob[4096][2048] at head column offset
#pragma unroll
    for (int m = 0; m < 2; ++m)
#pragma unroll
      for (int j = 0; j < 4; ++j) {
        const float inv = 1.0f / lsum[m][j];
        const size_t rbase = (size_t)(q0 + w * 32 + m * 16 + lg * 4 + j) * 2048 + h * 128 + l15;
#pragma unroll
        for (int vn = 0; vn < 8; ++vn)
          O[rbase + vn * 16] = (__bf16)(o_acc[m][vn][j] * inv);
      }
  }
}

// ---------------- launch ----------------

extern "C" void kernel_launch(void* const* d_in, const int* in_sizes, int n_in,
                              void* d_out, int out_size, void* d_ws, size_t ws_size,
                              hipStream_t stream) {
  const float* x    = (const float*)d_in[0];
  const float* fcos = (const float*)d_in[1];
  const float* fsin = (const float*)d_in[2];
  // d_in[3] = mask: implied by causal structure, unused
  const float* wq   = (const float*)d_in[4];
  const float* wkva = (const float*)d_in[5];
  const float* kvw  = (const float*)d_in[6];
  const float* wkvb = (const float*)d_in[7];
  const float* wo   = (const float*)d_in[8];
  float* out = (float*)d_out;
  char* ws = (char*)d_ws;

  __bf16* xb    = (__bf16*)(ws + 0);           // 16,777,216
  __bf16* wqT   = (__bf16*)(ws + 16777216);    // 12,582,912  [3072][2048]
  __bf16* wkvaT = (__bf16*)(ws + 29360128);    //  2,621,440  [640][2048] (zero-padded)
  __bf16* wkvbT = (__bf16*)(ws + 31981568);    //  4,194,304  [4096][512]
  __bf16* woT   = (__bf16*)(ws + 36175872);    //  8,388,608  [2048][2048]
  __bf16* qatt  = (__bf16*)(ws + 44564480);    // 25,165,824  [16][4096][192]
  __bf16* katt  = (__bf16*)(ws + 69730304);    // 25,165,824  [16][4096][192] swizzled
  __bf16* vT    = (__bf16*)(ws + 94896128);    // 16,777,216  [16][128][4096] swizzled
  __bf16* ob    = (__bf16*)(ws + 111673344);   // 16,777,216  [4096][2048]
  __bf16* ckv   = (__bf16*)(ws + 128450560);   //  4,194,304  [4096][512]
  __bf16* kpe   = (__bf16*)(ws + 132644864);   //    524,288  [4096][64]
  float*  kvraw = (float*)(ws + 133169152);    // 10,485,760  [4096][640]
  __bf16* kvup  = (__bf16*)(ws + 143654912);   // 33,554,432  [4096][4096]
  // total 177,209,344 bytes

  const double ms = 0.1 * log(40.0) + 1.0;
  const float SM_SCALE = (float)((1.0 / sqrt(192.0)) * ms * ms);

  convert_bf16<<<4096, 256, 0, stream>>>(x, xb, (size_t)SEQ * 2048);
  tconv<<<dim3(64, 96),  dim3(32, 8), 0, stream>>>(wq,   wqT,   2048, 3072, 3072);
  tconv<<<dim3(64, 20),  dim3(32, 8), 0, stream>>>(wkva, wkvaT, 2048, 576,  640);
  tconv<<<dim3(16, 128), dim3(32, 8), 0, stream>>>(wkvb, wkvbT, 512,  4096, 4096);
  tconv<<<dim3(64, 64),  dim3(32, 8), 0, stream>>>(wo,   woT,   2048, 2048, 2048);

  // q = x @ wq (softmax scale folded in; rope commutes with scalar), head layout, then RoPE
  gemm_nt<2><<<dim3(24, 32), 256, 0, stream>>>(xb, 2048, wqT, 2048, qatt, 192, 2048, SM_SCALE);
  rope_q<<<SEQ, 512, 0, stream>>>(qatt, fcos, fsin);
  // kv = x @ wkv_a (fp32)
  gemm_nt<0><<<dim3(5, 32), 256, 0, stream>>>(xb, 2048, wkvaT, 2048, kvraw, 640, 2048, 1.f);
  normrope_kv<<<SEQ, 256, 0, stream>>>(kvraw, kvw, fcos, fsin, ckv, kpe);
  // kv_up = rms_norm(kv_lat) @ wkv_b (bf16)
  gemm_nt<1><<<dim3(32, 32), 256, 0, stream>>>(ckv, 512, wkvbT, 512, kvup, 4096, 512, 1.f);
  scatter_kv<<<dim3(SEQ, 16), 192, 0, stream>>>(kvup, kpe, katt, vT);

  // fused causal flash attention -> ob
  flash_attn<<<256, 256, 0, stream>>>(qatt, katt, vT, ob);

  // out = o @ wo (fp32)
  gemm_nt<0><<<dim3(16, 32), 256, 0, stream>>>(ob, 2048, woT, 2048, out, 2048, 2048, 1.f);
}

// Round 7
// 590.488 us; speedup vs baseline: 1.5400x; 1.2249x over previous
//
#include <hip/hip_runtime.h>
#include <hip/hip_bf16.h>
#include <math.h>

// MLA forward, S=4096, DIM=2048, 16 heads, qk=192 (128 nope + 64 rope), v=128, kv_lora=512.
// bf16 MFMA; NT GEMMs for projections; fused flash attention (causal) with SWAPPED QK^T
// (S^T = K*Q -> lane-local softmax, 2 shfl_xor per reduce), cheap P round-trip
// (8x ds_write_b32 + 4x ds_read_b128, XOR-swizzled), Tq=64, grid 512 = 2 blocks/CU,
// uniform 65 kv-iters per block via (63-v, v) pass pairing. K double-buffered (hidden),
// V single-buffered (drain covered by partner block).
// r6->r7 fix: causal mask gate uses wave MIN q (kv0+63 > q0+w*16), not max q.

constexpr int SEQ = 4096;

typedef __bf16 bf16x8 __attribute__((ext_vector_type(8)));
typedef float f32x4 __attribute__((ext_vector_type(4)));

__device__ __forceinline__ void gload16(const __bf16* g, __bf16* l) {
  __builtin_amdgcn_global_load_lds(
      (__attribute__((address_space(1))) void*)const_cast<__bf16*>(g),
      (__attribute__((address_space(3))) void*)l, 16, 0, 0);
}

__device__ __forceinline__ unsigned pack_bf16(float a, float b) {
  __bf16 x = (__bf16)a, y = (__bf16)b;
  unsigned short ux = __builtin_bit_cast(unsigned short, x);
  unsigned short uy = __builtin_bit_cast(unsigned short, y);
  return (unsigned)ux | ((unsigned)uy << 16);
}

// ---------------- elementwise / prep kernels ----------------

__global__ void convert_bf16(const float* __restrict__ in, __bf16* __restrict__ out, size_t n) {
  size_t i = ((size_t)blockIdx.x * blockDim.x + threadIdx.x) * 8;
  if (i >= n) return;
  float4 a = *(const float4*)(in + i);
  float4 b = *(const float4*)(in + i + 4);
  bf16x8 v = { (__bf16)a.x,(__bf16)a.y,(__bf16)a.z,(__bf16)a.w,
               (__bf16)b.x,(__bf16)b.y,(__bf16)b.z,(__bf16)b.w };
  *(bf16x8*)(out + i) = v;
}

// in[K][N] fp32 (row stride N) -> out[Nout][K] bf16, rows n>=N zero-padded.
__global__ void tconv(const float* __restrict__ in, __bf16* __restrict__ out,
                      int K, int N, int Nout) {
  __shared__ float tile[32][33];
  const int kb = blockIdx.x * 32;
  const int nb = blockIdx.y * 32;
  const int tx = threadIdx.x, ty = threadIdx.y;
#pragma unroll
  for (int i = 0; i < 32; i += 8) {
    const int k = kb + ty + i, n = nb + tx;
    tile[ty + i][tx] = (n < N) ? in[(size_t)k * N + n] : 0.f;
  }
  __syncthreads();
#pragma unroll
  for (int i = 0; i < 32; i += 8) {
    const int n = nb + ty + i, k = kb + tx;
    out[(size_t)n * K + k] = (__bf16)tile[tx][ty + i];
  }
}

// in-place RoPE on q_attn[h][s][128..191]; block = 512 thr (16 heads x 32 pairs), grid = SEQ
__global__ void rope_q(__bf16* __restrict__ q, const float* __restrict__ fcos,
                       const float* __restrict__ fsin) {
  const int s = blockIdx.x;
  const int t = threadIdx.x;
  const int h = t >> 5, j = t & 31;
  const float c = fcos[s * 32 + j], sn = fsin[s * 32 + j];
  __bf16* p = q + ((size_t)h * SEQ + s) * 192 + 128 + 2 * j;
  const float xr = (float)p[0], xi = (float)p[1];
  p[0] = (__bf16)(xr * c - xi * sn);
  p[1] = (__bf16)(xr * sn + xi * c);
}

// RMS-norm kv_lat -> ckv bf16; RoPE k_pe -> kpe bf16. block 256, grid SEQ.
__global__ void normrope_kv(const float* __restrict__ kvraw, const float* __restrict__ w,
                            const float* __restrict__ fcos, const float* __restrict__ fsin,
                            __bf16* __restrict__ ckv, __bf16* __restrict__ kpe) {
  const int s = blockIdx.x, t = threadIdx.x;
  const float* row = kvraw + (size_t)s * 640;
  const float x0 = row[t], x1 = row[t + 256];
  __shared__ float red[256];
  red[t] = x0 * x0 + x1 * x1;
  __syncthreads();
  for (int k = 128; k > 0; k >>= 1) { if (t < k) red[t] += red[t + k]; __syncthreads(); }
  const float r = rsqrtf(red[0] / 512.f + 1e-6f);
  ckv[(size_t)s * 512 + t]       = (__bf16)(x0 * r * w[t]);
  ckv[(size_t)s * 512 + t + 256] = (__bf16)(x1 * r * w[t + 256]);
  if (t < 32) {
    const float c = fcos[s * 32 + t], sn = fsin[s * 32 + t];
    const float xr = row[512 + 2 * t], xi = row[513 + 2 * t];
    kpe[(size_t)s * 64 + 2 * t]     = (__bf16)(xr * c - xi * sn);
    kpe[(size_t)s * 64 + 2 * t + 1] = (__bf16)(xr * sn + xi * c);
  }
}

// Scatter to SWIZZLED attention layouts:
//  katt[h][s][col'] with col' = ((col/8 ^ (s&7))*8 | col%8)   (192 cols: 128 nope + 64 rope)
//  vT[h][d][s'] with s' swizzling the 8-elem chunk within each 64-kv tile by (d&7)
__global__ void scatter_kv(const __bf16* __restrict__ kvup, const __bf16* __restrict__ kpe,
                           __bf16* __restrict__ katt, __bf16* __restrict__ vT) {
  const int s = blockIdx.x, h = blockIdx.y, t = threadIdx.x;
  const size_t kbase = ((size_t)h * SEQ + s) * 192;
  const int r7 = s & 7;
  if (t < 128) {
    const int col = t;
    katt[kbase + ((((col >> 3) ^ r7) << 3) | (col & 7))] =
        kvup[(size_t)s * 4096 + h * 256 + t];
    const int sw = (s & ~63) | ((((s >> 3) & 7) ^ (t & 7)) << 3) | (s & 7);
    vT[((size_t)h * 128 + t) * SEQ + sw] = kvup[(size_t)s * 4096 + h * 256 + 128 + t];
  } else {
    const int col = t;  // 128..191
    katt[kbase + ((((col >> 3) ^ r7) << 3) | (col & 7))] = kpe[(size_t)s * 64 + (t - 128)];
  }
}

// ---------------- NT GEMM: C[M][N] = A[M][K] * B[N][K]^T ----------------
// 128x128 tile, 4 waves (2x2), BK=64, global_load_lds(16B) staging.
// OUT_MODE 0: fp32 row-major; 1: bf16 row-major; 2: bf16 q-head layout [c/192][r][c%192]
template<int OUT_MODE>
__global__ __launch_bounds__(256) void gemm_nt(
    const __bf16* __restrict__ A, int lda,
    const __bf16* __restrict__ B, int ldb,
    void* __restrict__ Cout, int ldc,
    int K, float scale)
{
  const int row0 = blockIdx.y * 128;
  const int col0 = blockIdx.x * 128;

  __shared__ __bf16 As[128 * 64];
  __shared__ __bf16 Bs[128 * 64];

  const int t = threadIdx.x;
  const int lane = t & 63;
  const int wid = t >> 6;
  const int wr = (wid >> 1) * 64;
  const int wc = (wid & 1) * 64;

  const int ar = t >> 3;          // 0..31
  const int ac = (t & 7) * 8;     // 0..56
  const __bf16* ag = A + (size_t)(row0 + ar) * lda + ac;
  const __bf16* bg = B + (size_t)(col0 + ar) * ldb + ac;
  const int loff = ar * 64 + ac;

  f32x4 acc[4][4] = {};

  for (int k0 = 0; k0 < K; k0 += 64) {
#pragma unroll
    for (int i = 0; i < 4; ++i) {
      gload16(ag + (size_t)(i * 32) * lda + k0, &As[loff + i * 32 * 64]);
      gload16(bg + (size_t)(i * 32) * ldb + k0, &Bs[loff + i * 32 * 64]);
    }
    __syncthreads();
    const int ro = lane & 15;
#pragma unroll
    for (int ks = 0; ks < 2; ++ks) {
      const int ko = ks * 32 + (lane >> 4) * 8;
      bf16x8 af[4], bfr[4];
#pragma unroll
      for (int x = 0; x < 4; ++x) {
        af[x]  = *(const bf16x8*)&As[(wr + x * 16 + ro) * 64 + ko];
        bfr[x] = *(const bf16x8*)&Bs[(wc + x * 16 + ro) * 64 + ko];
      }
#pragma unroll
      for (int x = 0; x < 4; ++x)
#pragma unroll
        for (int y = 0; y < 4; ++y)
          acc[x][y] = __builtin_amdgcn_mfma_f32_16x16x32_bf16(af[x], bfr[y], acc[x][y], 0, 0, 0);
    }
    __syncthreads();
  }

  const int lr = (lane >> 4) * 4;
  const int lc = lane & 15;
#pragma unroll
  for (int x = 0; x < 4; ++x)
#pragma unroll
    for (int y = 0; y < 4; ++y)
#pragma unroll
      for (int j = 0; j < 4; ++j) {
        const int r = row0 + wr + x * 16 + lr + j;
        const int c = col0 + wc + y * 16 + lc;
        const float v = acc[x][y][j] * scale;
        if (OUT_MODE == 0) {
          ((float*)Cout)[(size_t)r * ldc + c] = v;
        } else if (OUT_MODE == 1) {
          ((__bf16*)Cout)[(size_t)r * ldc + c] = (__bf16)v;
        } else {
          const int h = c / 192;
          const int d = c - h * 192;
          ((__bf16*)Cout)[((size_t)h * SEQ + r) * 192 + d] = (__bf16)v;
        }
      }
}

// ---------------- fused flash attention (causal, swapped-QK^T) ----------------
// Grid 512: 16 heads x 32 slots; 2 blocks/CU. Each block: 2 passes, qt = 63-v then v
// -> uniform 65 kv-iters. 4 waves x 16 q-rows (Tq=64). KV-tile 64.
// S^T = mfma(K, Q): lane l15 = q-col, holds 16 kv values -> lane-local softmax
// (in-lane reduce + shfl_xor 16/32). P commit: 8 ds_write_b32, read back 4 ds_read_b128
// (XOR-swizzled, conflict-free). K dbuf (staging hidden), V single (drain at bar2).
// LDS 72KB -> 2 blocks/CU = 2 waves/SIMD.
__global__ __launch_bounds__(256, 2) void flash_attn(
    const __bf16* __restrict__ Q, const __bf16* __restrict__ Kt,
    const __bf16* __restrict__ Vt, __bf16* __restrict__ O)
{
  __shared__ __bf16 Ks[2][64 * 192];
  __shared__ __bf16 Vs[128 * 64];
  __shared__ __bf16 Ps[4 * 16 * 64];

  const int bid  = blockIdx.x;
  const int xcd  = bid & 7;
  const int slot = bid >> 3;               // 0..63
  const int h    = xcd * 2 + (slot & 1);   // 2 heads per XCD
  const int v    = slot >> 1;              // 0..31 (pair id)

  const int t = threadIdx.x;
  const int lane = t & 63;
  const int w = t >> 6;
  const int l15 = lane & 15;
  const int lg  = lane >> 4;    // 0..3
  const int fsrc = lg * 20;     // shfl src base: lg*16 + lg*4

  int gch[6];
#pragma unroll
  for (int j = 0; j < 6; ++j) gch[j] = ((j << 2) + w) * 64 + lane;

  const __bf16* kh = Kt + (size_t)h * SEQ * 192;
  const __bf16* vh = Vt + (size_t)h * 128 * SEQ;
  const int pbase = w * 1024;   // per-wave P region (16q x 64kv)

#pragma unroll 1
  for (int pass = 0; pass < 2; ++pass) {
    const int qt = pass ? v : (63 - v);
    const int q0 = qt << 6;
    const int nt = qt + 1;

    // Q fragments (B-operand layout): lane l15 = q-col (q0 + w*16 + l15), k = kf*32 + lg*8
    bf16x8 qf[6];
    {
      const __bf16* qbase = Q + ((size_t)h * SEQ + q0 + w * 16 + l15) * 192 + lg * 8;
#pragma unroll
      for (int kf = 0; kf < 6; ++kf)
        qf[kf] = *(const bf16x8*)(qbase + kf * 32);
    }

    f32x4 o_acc[8] = {};
    float mrow = -1e30f, lsum = 0.f;

    // prologue: stage K(0) -> Ks[0], V(0) -> Vs
#pragma unroll
    for (int j = 0; j < 6; ++j) gload16(kh + gch[j] * 8, &Ks[0][gch[j] * 8]);
#pragma unroll
    for (int j = 0; j < 4; ++j)
      gload16(vh + (size_t)(gch[j] >> 3) * SEQ + (gch[j] & 7) * 8, &Vs[gch[j] * 8]);
    __syncthreads();

    int cur = 0;
#pragma unroll 1
    for (int ti = 0; ti < nt; ++ti) {
      const int kv0 = ti << 6;

      // stage NEXT K tile into the idle buffer (fully hidden under compute)
      if (ti + 1 < nt) {
        const __bf16* ksrc = kh + (size_t)(kv0 + 64) * 192;
#pragma unroll
        for (int j = 0; j < 6; ++j) gload16(ksrc + gch[j] * 8, &Ks[cur ^ 1][gch[j] * 8]);
      }

      const __bf16* KsC = Ks[cur];

      // S^T = K * Q : st[n][j] = S[kv = kv0 + n*16 + lg*4 + j][q = q0 + w*16 + l15]
      f32x4 st[4] = {};
#pragma unroll
      for (int kf = 0; kf < 6; ++kf) {
        bf16x8 kb[4];
#pragma unroll
        for (int n = 0; n < 4; ++n) {
          const int r = n * 16 + l15;
          const int ch = (kf * 4 + lg) ^ (r & 7);
          kb[n] = *(const bf16x8*)&KsC[r * 192 + ch * 8];
        }
#pragma unroll
        for (int n = 0; n < 4; ++n)
          st[n] = __builtin_amdgcn_mfma_f32_16x16x32_bf16(kb[n], qf[kf], st[n], 0, 0, 0);
      }

      // causal mask: fire when tile max-kv exceeds wave MIN q (diagonal tile, all waves)
      if (kv0 + 63 > q0 + w * 16) {
        const int qa = q0 + w * 16 + l15;
#pragma unroll
        for (int n = 0; n < 4; ++n)
#pragma unroll
          for (int j = 0; j < 4; ++j)
            if (kv0 + n * 16 + lg * 4 + j > qa) st[n][j] = -1e30f;
      }

      // online softmax for q = l15 (lane-local 16 kv values + cross-lg combine)
      f32x4 t01, t23, tm;
#pragma unroll
      for (int j = 0; j < 4; ++j) {
        t01[j] = fmaxf(st[0][j], st[1][j]);
        t23[j] = fmaxf(st[2][j], st[3][j]);
        tm[j]  = fmaxf(t01[j], t23[j]);
      }
      float pm = fmaxf(fmaxf(tm[0], tm[1]), fmaxf(tm[2], tm[3]));
      pm = fmaxf(pm, __shfl_xor(pm, 16));
      pm = fmaxf(pm, __shfl_xor(pm, 32));
      const float nm  = fmaxf(mrow, pm);
      const float fac = __expf(mrow - nm);
      mrow = nm;
      float rs = 0.f;
#pragma unroll
      for (int n = 0; n < 4; ++n)
#pragma unroll
        for (int j = 0; j < 4; ++j) {
          const float e = __expf(st[n][j] - nm);
          st[n][j] = e;
          rs += e;
        }
      rs += __shfl_xor(rs, 16);
      rs += __shfl_xor(rs, 32);
      lsum = lsum * fac + rs;

      // rescale o_acc: broadcast fac from the lane owning q-row lg*4+j
      float fj[4];
#pragma unroll
      for (int j = 0; j < 4; ++j) fj[j] = __shfl(fac, fsrc + j);
#pragma unroll
      for (int vn = 0; vn < 8; ++vn)
#pragma unroll
        for (int j = 0; j < 4; ++j) o_acc[vn][j] *= fj[j];

      // commit P: row = q (l15), cols kv (lane-contiguous pairs), XOR-swizzled
#pragma unroll
      for (int n = 0; n < 4; ++n) {
        const int chunk = n * 2 + (lg >> 1);
        const int sw = ((chunk ^ (l15 & 7)) << 3) + ((lg & 1) << 2);
        *(unsigned*)&Ps[pbase + l15 * 64 + sw]     = pack_bf16(st[n][0], st[n][1]);
        *(unsigned*)&Ps[pbase + l15 * 64 + sw + 2] = pack_bf16(st[n][2], st[n][3]);
      }

      // PV: O += P * V   (A = P rows q, B = V cols d)
#pragma unroll
      for (int kf2 = 0; kf2 < 2; ++kf2) {
        const bf16x8 pa = *(const bf16x8*)
            &Ps[pbase + l15 * 64 + (((kf2 * 4 + lg) ^ (l15 & 7)) << 3)];
#pragma unroll
        for (int vn = 0; vn < 8; ++vn) {
          const int r = vn * 16 + l15;
          const int ch = (kf2 * 4 + lg) ^ (r & 7);
          const bf16x8 vb = *(const bf16x8*)&Vs[r * 64 + ch * 8];
          o_acc[vn] = __builtin_amdgcn_mfma_f32_16x16x32_bf16(pa, vb, o_acc[vn], 0, 0, 0);
        }
      }
      __syncthreads();   // all waves done with Vs + Ks[cur]

      // stage NEXT V tile (single-buffered; drain at the next barrier)
      if (ti + 1 < nt) {
        const __bf16* vsrc = vh + kv0 + 64;
#pragma unroll
        for (int j = 0; j < 4; ++j)
          gload16(vsrc + (size_t)(gch[j] >> 3) * SEQ + (gch[j] & 7) * 8, &Vs[gch[j] * 8]);
      }
      __syncthreads();   // V(t+1) ready; K(t+1) landed long ago
      cur ^= 1;
    }

    // epilogue: normalize and store
    {
      const float inv = 1.0f / lsum;
      float ivj[4];
#pragma unroll
      for (int j = 0; j < 4; ++j) ivj[j] = __shfl(inv, fsrc + j);
#pragma unroll
      for (int vn = 0; vn < 8; ++vn)
#pragma unroll
        for (int j = 0; j < 4; ++j) {
          const size_t r = (size_t)(q0 + w * 16 + lg * 4 + j);
          O[r * 2048 + h * 128 + vn * 16 + l15] = (__bf16)(o_acc[vn][j] * ivj[j]);
        }
    }
  }
}

// ---------------- launch ----------------

extern "C" void kernel_launch(void* const* d_in, const int* in_sizes, int n_in,
                              void* d_out, int out_size, void* d_ws, size_t ws_size,
                              hipStream_t stream) {
  const float* x    = (const float*)d_in[0];
  const float* fcos = (const float*)d_in[1];
  const float* fsin = (const float*)d_in[2];
  // d_in[3] = mask: implied by causal structure, unused
  const float* wq   = (const float*)d_in[4];
  const float* wkva = (const float*)d_in[5];
  const float* kvw  = (const float*)d_in[6];
  const float* wkvb = (const float*)d_in[7];
  const float* wo   = (const float*)d_in[8];
  float* out = (float*)d_out;
  char* ws = (char*)d_ws;

  __bf16* xb    = (__bf16*)(ws + 0);           // 16,777,216
  __bf16* wqT   = (__bf16*)(ws + 16777216);    // 12,582,912  [3072][2048]
  __bf16* wkvaT = (__bf16*)(ws + 29360128);    //  2,621,440  [640][2048] (zero-padded)
  __bf16* wkvbT = (__bf16*)(ws + 31981568);    //  4,194,304  [4096][512]
  __bf16* woT   = (__bf16*)(ws + 36175872);    //  8,388,608  [2048][2048]
  __bf16* qatt  = (__bf16*)(ws + 44564480);    // 25,165,824  [16][4096][192]
  __bf16* katt  = (__bf16*)(ws + 69730304);    // 25,165,824  [16][4096][192] swizzled
  __bf16* vT    = (__bf16*)(ws + 94896128);    // 16,777,216  [16][128][4096] swizzled
  __bf16* ob    = (__bf16*)(ws + 111673344);   // 16,777,216  [4096][2048]
  __bf16* ckv   = (__bf16*)(ws + 128450560);   //  4,194,304  [4096][512]
  __bf16* kpe   = (__bf16*)(ws + 132644864);   //    524,288  [4096][64]
  float*  kvraw = (float*)(ws + 133169152);    // 10,485,760  [4096][640]
  __bf16* kvup  = (__bf16*)(ws + 143654912);   // 33,554,432  [4096][4096]
  // total 177,209,344 bytes

  const double ms = 0.1 * log(40.0) + 1.0;
  const float SM_SCALE = (float)((1.0 / sqrt(192.0)) * ms * ms);

  convert_bf16<<<4096, 256, 0, stream>>>(x, xb, (size_t)SEQ * 2048);
  tconv<<<dim3(64, 96),  dim3(32, 8), 0, stream>>>(wq,   wqT,   2048, 3072, 3072);
  tconv<<<dim3(64, 20),  dim3(32, 8), 0, stream>>>(wkva, wkvaT, 2048, 576,  640);
  tconv<<<dim3(16, 128), dim3(32, 8), 0, stream>>>(wkvb, wkvbT, 512,  4096, 4096);
  tconv<<<dim3(64, 64),  dim3(32, 8), 0, stream>>>(wo,   woT,   2048, 2048, 2048);

  // q = x @ wq (softmax scale folded in; rope commutes with scalar), head layout, then RoPE
  gemm_nt<2><<<dim3(24, 32), 256, 0, stream>>>(xb, 2048, wqT, 2048, qatt, 192, 2048, SM_SCALE);
  rope_q<<<SEQ, 512, 0, stream>>>(qatt, fcos, fsin);
  // kv = x @ wkv_a (fp32)
  gemm_nt<0><<<dim3(5, 32), 256, 0, stream>>>(xb, 2048, wkvaT, 2048, kvraw, 640, 2048, 1.f);
  normrope_kv<<<SEQ, 256, 0, stream>>>(kvraw, kvw, fcos, fsin, ckv, kpe);
  // kv_up = rms_norm(kv_lat) @ wkv_b (bf16)
  gemm_nt<1><<<dim3(32, 32), 256, 0, stream>>>(ckv, 512, wkvbT, 512, kvup, 4096, 512, 1.f);
  scatter_kv<<<dim3(SEQ, 16), 192, 0, stream>>>(kvup, kpe, katt, vT);

  // fused causal flash attention -> ob
  flash_attn<<<512, 256, 0, stream>>>(qatt, katt, vT, ob);

  // out = o @ wo (fp32)
  gemm_nt<0><<<dim3(16, 32), 256, 0, stream>>>(ob, 2048, woT, 2048, out, 2048, 2048, 1.f);
}

// Round 8
// 571.858 us; speedup vs baseline: 1.5901x; 1.0326x over previous
//
#include <hip/hip_runtime.h>
#include <hip/hip_bf16.h>
#include <math.h>

// MLA forward, S=4096, DIM=2048, 16 heads, qk=192 (128 nope + 64 rope), v=128, kv_lora=512.
// bf16 MFMA; NT GEMMs for projections; fused flash attention (causal, swapped QK^T,
// lane-local softmax, T5 setprio). r7->r8: scatter_kv split into scatter_k (coalesced)
// + transpose_v (LDS-tiled, full-cacheline swizzled writes) — kills ~32x vT write
// amplification; setprio(1) around flash MFMA clusters.

constexpr int SEQ = 4096;

typedef __bf16 bf16x8 __attribute__((ext_vector_type(8)));
typedef float f32x4 __attribute__((ext_vector_type(4)));

__device__ __forceinline__ void gload16(const __bf16* g, __bf16* l) {
  __builtin_amdgcn_global_load_lds(
      (__attribute__((address_space(1))) void*)const_cast<__bf16*>(g),
      (__attribute__((address_space(3))) void*)l, 16, 0, 0);
}

__device__ __forceinline__ unsigned pack_bf16(float a, float b) {
  __bf16 x = (__bf16)a, y = (__bf16)b;
  unsigned short ux = __builtin_bit_cast(unsigned short, x);
  unsigned short uy = __builtin_bit_cast(unsigned short, y);
  return (unsigned)ux | ((unsigned)uy << 16);
}

// ---------------- elementwise / prep kernels ----------------

__global__ void convert_bf16(const float* __restrict__ in, __bf16* __restrict__ out, size_t n) {
  size_t i = ((size_t)blockIdx.x * blockDim.x + threadIdx.x) * 8;
  if (i >= n) return;
  float4 a = *(const float4*)(in + i);
  float4 b = *(const float4*)(in + i + 4);
  bf16x8 v = { (__bf16)a.x,(__bf16)a.y,(__bf16)a.z,(__bf16)a.w,
               (__bf16)b.x,(__bf16)b.y,(__bf16)b.z,(__bf16)b.w };
  *(bf16x8*)(out + i) = v;
}

// in[K][N] fp32 (row stride N) -> out[Nout][K] bf16, rows n>=N zero-padded.
__global__ void tconv(const float* __restrict__ in, __bf16* __restrict__ out,
                      int K, int N, int Nout) {
  __shared__ float tile[32][33];
  const int kb = blockIdx.x * 32;
  const int nb = blockIdx.y * 32;
  const int tx = threadIdx.x, ty = threadIdx.y;
#pragma unroll
  for (int i = 0; i < 32; i += 8) {
    const int k = kb + ty + i, n = nb + tx;
    tile[ty + i][tx] = (n < N) ? in[(size_t)k * N + n] : 0.f;
  }
  __syncthreads();
#pragma unroll
  for (int i = 0; i < 32; i += 8) {
    const int n = nb + ty + i, k = kb + tx;
    out[(size_t)n * K + k] = (__bf16)tile[tx][ty + i];
  }
}

// in-place RoPE on q_attn[h][s][128..191]; block = 512 thr (16 heads x 32 pairs), grid = SEQ
__global__ void rope_q(__bf16* __restrict__ q, const float* __restrict__ fcos,
                       const float* __restrict__ fsin) {
  const int s = blockIdx.x;
  const int t = threadIdx.x;
  const int h = t >> 5, j = t & 31;
  const float c = fcos[s * 32 + j], sn = fsin[s * 32 + j];
  __bf16* p = q + ((size_t)h * SEQ + s) * 192 + 128 + 2 * j;
  const float xr = (float)p[0], xi = (float)p[1];
  p[0] = (__bf16)(xr * c - xi * sn);
  p[1] = (__bf16)(xr * sn + xi * c);
}

// RMS-norm kv_lat -> ckv bf16; RoPE k_pe -> kpe bf16. block 256, grid SEQ.
__global__ void normrope_kv(const float* __restrict__ kvraw, const float* __restrict__ w,
                            const float* __restrict__ fcos, const float* __restrict__ fsin,
                            __bf16* __restrict__ ckv, __bf16* __restrict__ kpe) {
  const int s = blockIdx.x, t = threadIdx.x;
  const float* row = kvraw + (size_t)s * 640;
  const float x0 = row[t], x1 = row[t + 256];
  __shared__ float red[256];
  red[t] = x0 * x0 + x1 * x1;
  __syncthreads();
  for (int k = 128; k > 0; k >>= 1) { if (t < k) red[t] += red[t + k]; __syncthreads(); }
  const float r = rsqrtf(red[0] / 512.f + 1e-6f);
  ckv[(size_t)s * 512 + t]       = (__bf16)(x0 * r * w[t]);
  ckv[(size_t)s * 512 + t + 256] = (__bf16)(x1 * r * w[t + 256]);
  if (t < 32) {
    const float c = fcos[s * 32 + t], sn = fsin[s * 32 + t];
    const float xr = row[512 + 2 * t], xi = row[513 + 2 * t];
    kpe[(size_t)s * 64 + 2 * t]     = (__bf16)(xr * c - xi * sn);
    kpe[(size_t)s * 64 + 2 * t + 1] = (__bf16)(xr * sn + xi * c);
  }
}

// K scatter (coalesced): katt[h][s][col'] with col' = ((col/8 ^ (s&7))*8 | col%8)
__global__ void scatter_k(const __bf16* __restrict__ kvup, const __bf16* __restrict__ kpe,
                          __bf16* __restrict__ katt) {
  const int s = blockIdx.x, h = blockIdx.y, t = threadIdx.x;
  const size_t kbase = ((size_t)h * SEQ + s) * 192;
  const int r7 = s & 7;
  const __bf16 val = (t < 128) ? kvup[(size_t)s * 4096 + h * 256 + t]
                               : kpe[(size_t)s * 64 + (t - 128)];
  katt[kbase + ((((t >> 3) ^ r7) << 3) | (t & 7))] = val;
}

// V transpose, LDS-tiled: kvup[s][h*256+128+d] -> vT[h][d][sw(s,d)].
// Tile 64 s x 32 d. Reads coalesced along d; writes cover full 64-s swizzle
// windows (128B) per d-row -> no write amplification. grid (64,4,16), block 256.
__global__ void transpose_v(const __bf16* __restrict__ kvup, __bf16* __restrict__ vT) {
  __shared__ __bf16 tile[64][33];
  const int s0 = blockIdx.x * 64;
  const int d0 = blockIdx.y * 32;
  const int h  = blockIdx.z;
  const int t  = threadIdx.x;
  const int dx = t & 31, sr = t >> 5;          // read: 8 s-rows per pass
#pragma unroll
  for (int i = 0; i < 8; ++i)
    tile[sr + i * 8][dx] =
        kvup[(size_t)(s0 + sr + i * 8) * 4096 + h * 256 + 128 + d0 + dx];
  __syncthreads();
  const int sx = t & 63, dr = t >> 6;          // write: 4 d-rows per pass
#pragma unroll
  for (int i = 0; i < 8; ++i) {
    const int d = d0 + dr + i * 4;
    const int s = s0 + sx;
    const int sw = (s & ~63) | ((((s >> 3) & 7) ^ (d & 7)) << 3) | (s & 7);
    vT[((size_t)h * 128 + d) * SEQ + sw] = tile[sx][dr + i * 4];
  }
}

// ---------------- NT GEMM: C[M][N] = A[M][K] * B[N][K]^T ----------------
// 128x128 tile, 4 waves (2x2), BK=64, global_load_lds(16B) staging.
// OUT_MODE 0: fp32 row-major; 1: bf16 row-major; 2: bf16 q-head layout [c/192][r][c%192]
template<int OUT_MODE>
__global__ __launch_bounds__(256) void gemm_nt(
    const __bf16* __restrict__ A, int lda,
    const __bf16* __restrict__ B, int ldb,
    void* __restrict__ Cout, int ldc,
    int K, float scale)
{
  const int row0 = blockIdx.y * 128;
  const int col0 = blockIdx.x * 128;

  __shared__ __bf16 As[128 * 64];
  __shared__ __bf16 Bs[128 * 64];

  const int t = threadIdx.x;
  const int lane = t & 63;
  const int wid = t >> 6;
  const int wr = (wid >> 1) * 64;
  const int wc = (wid & 1) * 64;

  const int ar = t >> 3;          // 0..31
  const int ac = (t & 7) * 8;     // 0..56
  const __bf16* ag = A + (size_t)(row0 + ar) * lda + ac;
  const __bf16* bg = B + (size_t)(col0 + ar) * ldb + ac;
  const int loff = ar * 64 + ac;

  f32x4 acc[4][4] = {};

  for (int k0 = 0; k0 < K; k0 += 64) {
#pragma unroll
    for (int i = 0; i < 4; ++i) {
      gload16(ag + (size_t)(i * 32) * lda + k0, &As[loff + i * 32 * 64]);
      gload16(bg + (size_t)(i * 32) * ldb + k0, &Bs[loff + i * 32 * 64]);
    }
    __syncthreads();
    const int ro = lane & 15;
#pragma unroll
    for (int ks = 0; ks < 2; ++ks) {
      const int ko = ks * 32 + (lane >> 4) * 8;
      bf16x8 af[4], bfr[4];
#pragma unroll
      for (int x = 0; x < 4; ++x) {
        af[x]  = *(const bf16x8*)&As[(wr + x * 16 + ro) * 64 + ko];
        bfr[x] = *(const bf16x8*)&Bs[(wc + x * 16 + ro) * 64 + ko];
      }
#pragma unroll
      for (int x = 0; x < 4; ++x)
#pragma unroll
        for (int y = 0; y < 4; ++y)
          acc[x][y] = __builtin_amdgcn_mfma_f32_16x16x32_bf16(af[x], bfr[y], acc[x][y], 0, 0, 0);
    }
    __syncthreads();
  }

  const int lr = (lane >> 4) * 4;
  const int lc = lane & 15;
#pragma unroll
  for (int x = 0; x < 4; ++x)
#pragma unroll
    for (int y = 0; y < 4; ++y)
#pragma unroll
      for (int j = 0; j < 4; ++j) {
        const int r = row0 + wr + x * 16 + lr + j;
        const int c = col0 + wc + y * 16 + lc;
        const float v = acc[x][y][j] * scale;
        if (OUT_MODE == 0) {
          ((float*)Cout)[(size_t)r * ldc + c] = v;
        } else if (OUT_MODE == 1) {
          ((__bf16*)Cout)[(size_t)r * ldc + c] = (__bf16)v;
        } else {
          const int h = c / 192;
          const int d = c - h * 192;
          ((__bf16*)Cout)[((size_t)h * SEQ + r) * 192 + d] = (__bf16)v;
        }
      }
}

// ---------------- fused flash attention (causal, swapped-QK^T) ----------------
// Grid 512: 16 heads x 32 slots; 2 blocks/CU. Each block: 2 passes, qt = 63-v then v
// -> uniform 65 kv-iters. 4 waves x 16 q-rows (Tq=64). KV-tile 64.
// S^T = mfma(K, Q): lane l15 = q-col, holds 16 kv values -> lane-local softmax.
// K dbuf (staging hidden), V single (drain at bar2). setprio(1) around MFMA clusters
// (T5: independent co-resident blocks give scheduler role diversity). LDS 72KB.
__global__ __launch_bounds__(256, 2) void flash_attn(
    const __bf16* __restrict__ Q, const __bf16* __restrict__ Kt,
    const __bf16* __restrict__ Vt, __bf16* __restrict__ O)
{
  __shared__ __bf16 Ks[2][64 * 192];
  __shared__ __bf16 Vs[128 * 64];
  __shared__ __bf16 Ps[4 * 16 * 64];

  const int bid  = blockIdx.x;
  const int xcd  = bid & 7;
  const int slot = bid >> 3;               // 0..63
  const int h    = xcd * 2 + (slot & 1);   // 2 heads per XCD
  const int v    = slot >> 1;              // 0..31 (pair id)

  const int t = threadIdx.x;
  const int lane = t & 63;
  const int w = t >> 6;
  const int l15 = lane & 15;
  const int lg  = lane >> 4;    // 0..3
  const int fsrc = lg * 20;     // shfl src base: lg*16 + lg*4

  int gch[6];
#pragma unroll
  for (int j = 0; j < 6; ++j) gch[j] = ((j << 2) + w) * 64 + lane;

  const __bf16* kh = Kt + (size_t)h * SEQ * 192;
  const __bf16* vh = Vt + (size_t)h * 128 * SEQ;
  const int pbase = w * 1024;   // per-wave P region (16q x 64kv)

#pragma unroll 1
  for (int pass = 0; pass < 2; ++pass) {
    const int qt = pass ? v : (63 - v);
    const int q0 = qt << 6;
    const int nt = qt + 1;

    // Q fragments (B-operand layout): lane l15 = q-col (q0 + w*16 + l15), k = kf*32 + lg*8
    bf16x8 qf[6];
    {
      const __bf16* qbase = Q + ((size_t)h * SEQ + q0 + w * 16 + l15) * 192 + lg * 8;
#pragma unroll
      for (int kf = 0; kf < 6; ++kf)
        qf[kf] = *(const bf16x8*)(qbase + kf * 32);
    }

    f32x4 o_acc[8] = {};
    float mrow = -1e30f, lsum = 0.f;

    // prologue: stage K(0) -> Ks[0], V(0) -> Vs
#pragma unroll
    for (int j = 0; j < 6; ++j) gload16(kh + gch[j] * 8, &Ks[0][gch[j] * 8]);
#pragma unroll
    for (int j = 0; j < 4; ++j)
      gload16(vh + (size_t)(gch[j] >> 3) * SEQ + (gch[j] & 7) * 8, &Vs[gch[j] * 8]);
    __syncthreads();

    int cur = 0;
#pragma unroll 1
    for (int ti = 0; ti < nt; ++ti) {
      const int kv0 = ti << 6;

      // stage NEXT K tile into the idle buffer (fully hidden under compute)
      if (ti + 1 < nt) {
        const __bf16* ksrc = kh + (size_t)(kv0 + 64) * 192;
#pragma unroll
        for (int j = 0; j < 6; ++j) gload16(ksrc + gch[j] * 8, &Ks[cur ^ 1][gch[j] * 8]);
      }

      const __bf16* KsC = Ks[cur];

      // S^T = K * Q : st[n][j] = S[kv = kv0 + n*16 + lg*4 + j][q = q0 + w*16 + l15]
      f32x4 st[4] = {};
      __builtin_amdgcn_s_setprio(1);
#pragma unroll
      for (int kf = 0; kf < 6; ++kf) {
        bf16x8 kb[4];
#pragma unroll
        for (int n = 0; n < 4; ++n) {
          const int r = n * 16 + l15;
          const int ch = (kf * 4 + lg) ^ (r & 7);
          kb[n] = *(const bf16x8*)&KsC[r * 192 + ch * 8];
        }
#pragma unroll
        for (int n = 0; n < 4; ++n)
          st[n] = __builtin_amdgcn_mfma_f32_16x16x32_bf16(kb[n], qf[kf], st[n], 0, 0, 0);
      }
      __builtin_amdgcn_s_setprio(0);

      // causal mask: fire when tile max-kv exceeds wave MIN q (diagonal tile, all waves)
      if (kv0 + 63 > q0 + w * 16) {
        const int qa = q0 + w * 16 + l15;
#pragma unroll
        for (int n = 0; n < 4; ++n)
#pragma unroll
          for (int j = 0; j < 4; ++j)
            if (kv0 + n * 16 + lg * 4 + j > qa) st[n][j] = -1e30f;
      }

      // online softmax for q = l15 (lane-local 16 kv values + cross-lg combine)
      f32x4 t01, t23, tm;
#pragma unroll
      for (int j = 0; j < 4; ++j) {
        t01[j] = fmaxf(st[0][j], st[1][j]);
        t23[j] = fmaxf(st[2][j], st[3][j]);
        tm[j]  = fmaxf(t01[j], t23[j]);
      }
      float pm = fmaxf(fmaxf(tm[0], tm[1]), fmaxf(tm[2], tm[3]));
      pm = fmaxf(pm, __shfl_xor(pm, 16));
      pm = fmaxf(pm, __shfl_xor(pm, 32));
      const float nm  = fmaxf(mrow, pm);
      const float fac = __expf(mrow - nm);
      mrow = nm;
      float rs = 0.f;
#pragma unroll
      for (int n = 0; n < 4; ++n)
#pragma unroll
        for (int j = 0; j < 4; ++j) {
          const float e = __expf(st[n][j] - nm);
          st[n][j] = e;
          rs += e;
        }
      rs += __shfl_xor(rs, 16);
      rs += __shfl_xor(rs, 32);
      lsum = lsum * fac + rs;

      // rescale o_acc: broadcast fac from the lane owning q-row lg*4+j
      float fj[4];
#pragma unroll
      for (int j = 0; j < 4; ++j) fj[j] = __shfl(fac, fsrc + j);
#pragma unroll
      for (int vn = 0; vn < 8; ++vn)
#pragma unroll
        for (int j = 0; j < 4; ++j) o_acc[vn][j] *= fj[j];

      // commit P: row = q (l15), cols kv (lane-contiguous pairs), XOR-swizzled
#pragma unroll
      for (int n = 0; n < 4; ++n) {
        const int chunk = n * 2 + (lg >> 1);
        const int sw = ((chunk ^ (l15 & 7)) << 3) + ((lg & 1) << 2);
        *(unsigned*)&Ps[pbase + l15 * 64 + sw]     = pack_bf16(st[n][0], st[n][1]);
        *(unsigned*)&Ps[pbase + l15 * 64 + sw + 2] = pack_bf16(st[n][2], st[n][3]);
      }

      // PV: O += P * V   (A = P rows q, B = V cols d)
      __builtin_amdgcn_s_setprio(1);
#pragma unroll
      for (int kf2 = 0; kf2 < 2; ++kf2) {
        const bf16x8 pa = *(const bf16x8*)
            &Ps[pbase + l15 * 64 + (((kf2 * 4 + lg) ^ (l15 & 7)) << 3)];
#pragma unroll
        for (int vn = 0; vn < 8; ++vn) {
          const int r = vn * 16 + l15;
          const int ch = (kf2 * 4 + lg) ^ (r & 7);
          const bf16x8 vb = *(const bf16x8*)&Vs[r * 64 + ch * 8];
          o_acc[vn] = __builtin_amdgcn_mfma_f32_16x16x32_bf16(pa, vb, o_acc[vn], 0, 0, 0);
        }
      }
      __builtin_amdgcn_s_setprio(0);
      __syncthreads();   // all waves done with Vs + Ks[cur]

      // stage NEXT V tile (single-buffered; drain at the next barrier)
      if (ti + 1 < nt) {
        const __bf16* vsrc = vh + kv0 + 64;
#pragma unroll
        for (int j = 0; j < 4; ++j)
          gload16(vsrc + (size_t)(gch[j] >> 3) * SEQ + (gch[j] & 7) * 8, &Vs[gch[j] * 8]);
      }
      __syncthreads();   // V(t+1) ready; K(t+1) landed long ago
      cur ^= 1;
    }

    // epilogue: normalize and store
    {
      const float inv = 1.0f / lsum;
      float ivj[4];
#pragma unroll
      for (int j = 0; j < 4; ++j) ivj[j] = __shfl(inv, fsrc + j);
#pragma unroll
      for (int vn = 0; vn < 8; ++vn)
#pragma unroll
        for (int j = 0; j < 4; ++j) {
          const size_t r = (size_t)(q0 + w * 16 + lg * 4 + j);
          O[r * 2048 + h * 128 + vn * 16 + l15] = (__bf16)(o_acc[vn][j] * ivj[j]);
        }
    }
  }
}

// ---------------- launch ----------------

extern "C" void kernel_launch(void* const* d_in, const int* in_sizes, int n_in,
                              void* d_out, int out_size, void* d_ws, size_t ws_size,
                              hipStream_t stream) {
  const float* x    = (const float*)d_in[0];
  const float* fcos = (const float*)d_in[1];
  const float* fsin = (const float*)d_in[2];
  // d_in[3] = mask: implied by causal structure, unused
  const float* wq   = (const float*)d_in[4];
  const float* wkva = (const float*)d_in[5];
  const float* kvw  = (const float*)d_in[6];
  const float* wkvb = (const float*)d_in[7];
  const float* wo   = (const float*)d_in[8];
  float* out = (float*)d_out;
  char* ws = (char*)d_ws;

  __bf16* xb    = (__bf16*)(ws + 0);           // 16,777,216
  __bf16* wqT   = (__bf16*)(ws + 16777216);    // 12,582,912  [3072][2048]
  __bf16* wkvaT = (__bf16*)(ws + 29360128);    //  2,621,440  [640][2048] (zero-padded)
  __bf16* wkvbT = (__bf16*)(ws + 31981568);    //  4,194,304  [4096][512]
  __bf16* woT   = (__bf16*)(ws + 36175872);    //  8,388,608  [2048][2048]
  __bf16* qatt  = (__bf16*)(ws + 44564480);    // 25,165,824  [16][4096][192]
  __bf16* katt  = (__bf16*)(ws + 69730304);    // 25,165,824  [16][4096][192] swizzled
  __bf16* vT    = (__bf16*)(ws + 94896128);    // 16,777,216  [16][128][4096] swizzled
  __bf16* ob    = (__bf16*)(ws + 111673344);   // 16,777,216  [4096][2048]
  __bf16* ckv   = (__bf16*)(ws + 128450560);   //  4,194,304  [4096][512]
  __bf16* kpe   = (__bf16*)(ws + 132644864);   //    524,288  [4096][64]
  float*  kvraw = (float*)(ws + 133169152);    // 10,485,760  [4096][640]
  __bf16* kvup  = (__bf16*)(ws + 143654912);   // 33,554,432  [4096][4096]
  // total 177,209,344 bytes

  const double ms = 0.1 * log(40.0) + 1.0;
  const float SM_SCALE = (float)((1.0 / sqrt(192.0)) * ms * ms);

  convert_bf16<<<4096, 256, 0, stream>>>(x, xb, (size_t)SEQ * 2048);
  tconv<<<dim3(64, 96),  dim3(32, 8), 0, stream>>>(wq,   wqT,   2048, 3072, 3072);
  tconv<<<dim3(64, 20),  dim3(32, 8), 0, stream>>>(wkva, wkvaT, 2048, 576,  640);
  tconv<<<dim3(16, 128), dim3(32, 8), 0, stream>>>(wkvb, wkvbT, 512,  4096, 4096);
  tconv<<<dim3(64, 64),  dim3(32, 8), 0, stream>>>(wo,   woT,   2048, 2048, 2048);

  // q = x @ wq (softmax scale folded in; rope commutes with scalar), head layout, then RoPE
  gemm_nt<2><<<dim3(24, 32), 256, 0, stream>>>(xb, 2048, wqT, 2048, qatt, 192, 2048, SM_SCALE);
  rope_q<<<SEQ, 512, 0, stream>>>(qatt, fcos, fsin);
  // kv = x @ wkv_a (fp32)
  gemm_nt<0><<<dim3(5, 32), 256, 0, stream>>>(xb, 2048, wkvaT, 2048, kvraw, 640, 2048, 1.f);
  normrope_kv<<<SEQ, 256, 0, stream>>>(kvraw, kvw, fcos, fsin, ckv, kpe);
  // kv_up = rms_norm(kv_lat) @ wkv_b (bf16)
  gemm_nt<1><<<dim3(32, 32), 256, 0, stream>>>(ckv, 512, wkvbT, 512, kvup, 4096, 512, 1.f);
  scatter_k<<<dim3(SEQ, 16), 192, 0, stream>>>(kvup, kpe, katt);
  transpose_v<<<dim3(64, 4, 16), 256, 0, stream>>>(kvup, vT);

  // fused causal flash attention -> ob
  flash_attn<<<512, 256, 0, stream>>>(qatt, katt, vT, ob);

  // out = o @ wo (fp32)
  gemm_nt<0><<<dim3(16, 32), 256, 0, stream>>>(ob, 2048, woT, 2048, out, 2048, 2048, 1.f);
}